// Round 1
// baseline (43984.271 us; speedup 1.0000x reference)
//
#include <hip/hip_runtime.h>
#include <hip/hip_bf16.h>
#include <stdint.h>

#define T_LEN 1024
#define NBATCH 32
#define HDIM 768
#define G3 2304
#define NBLK 48

typedef __attribute__((ext_vector_type(8))) short short8;
typedef __attribute__((ext_vector_type(4))) float f32x4;

__device__ __forceinline__ unsigned short f2bf(float f) {
  union { float f; unsigned u; } v; v.f = f;
  return (unsigned short)((v.u + 0x7FFFu + ((v.u >> 16) & 1u)) >> 16);
}
__device__ __forceinline__ float bf2f(unsigned hs) {  // low 16 bits used
  union { unsigned u; float f; } v; v.u = hs << 16; return v.f;
}
__device__ __forceinline__ unsigned pack2(float a, float b) {
  return (unsigned)f2bf(a) | ((unsigned)f2bf(b) << 16);
}
__device__ __forceinline__ float sigm(float x) { return 1.f / (1.f + __expf(-x)); }

// ---------------------------------------------------------------------------
// Input projection GEMM: xg[m][g] = sum_k A[m][k] * W[g][k] + bias(g)
//   A row m = t*32 + b ; A data = src[b][t] (or src[b][1023-t] if flip)
//   bias(g) = b_ih[g] + (g < 1536 ? b_hh[g] : 0)   (b_hhn stays in the scan)
//   output bf16, layout [t][b][2304]  (m-major == t,b-major)
// ---------------------------------------------------------------------------
__global__ __launch_bounds__(256) void gemm_xg(
    const float* __restrict__ src, const float* __restrict__ W,
    const float* __restrict__ b_ih, const float* __restrict__ b_hh,
    unsigned short* __restrict__ xg, int flip)
{
  __shared__ unsigned short As[128 * 40];
  __shared__ unsigned short Bs[128 * 40];

  const int bx = blockIdx.x % 18;   // N tile (2304/128)
  const int by = blockIdx.x / 18;   // M tile (32768/128)
  const int tid = threadIdx.x;
  const int lane = tid & 63;
  const int w = tid >> 6;
  const int wm = w & 1, wn = w >> 1;

  f32x4 acc[4][4];
#pragma unroll
  for (int i = 0; i < 4; i++)
#pragma unroll
    for (int j = 0; j < 4; j++) acc[i][j] = (f32x4){0.f, 0.f, 0.f, 0.f};

  const int r = tid >> 1;
  const int ch = (tid & 1) * 16;

  const int m = by * 128 + r;
  const int tt = m >> 5, bb = m & 31;
  const int srow = flip ? (bb * T_LEN + (T_LEN - 1 - tt)) : (bb * T_LEN + tt);
  const float* arow = src + (size_t)srow * HDIM;
  const int gn = bx * 128 + r;
  const float* brow = W + (size_t)gn * HDIM;

  for (int k0 = 0; k0 < HDIM; k0 += 32) {
    {
      const float4* pa = (const float4*)(arow + k0 + ch);
      float4 a0 = pa[0], a1 = pa[1], a2 = pa[2], a3 = pa[3];
      uint4 q0, q1;
      q0.x = pack2(a0.x, a0.y); q0.y = pack2(a0.z, a0.w);
      q0.z = pack2(a1.x, a1.y); q0.w = pack2(a1.z, a1.w);
      q1.x = pack2(a2.x, a2.y); q1.y = pack2(a2.z, a2.w);
      q1.z = pack2(a3.x, a3.y); q1.w = pack2(a3.z, a3.w);
      *(uint4*)&As[r * 40 + ch] = q0;
      *(uint4*)&As[r * 40 + ch + 8] = q1;

      const float4* pb = (const float4*)(brow + k0 + ch);
      float4 b0 = pb[0], b1 = pb[1], b2 = pb[2], b3 = pb[3];
      q0.x = pack2(b0.x, b0.y); q0.y = pack2(b0.z, b0.w);
      q0.z = pack2(b1.x, b1.y); q0.w = pack2(b1.z, b1.w);
      q1.x = pack2(b2.x, b2.y); q1.y = pack2(b2.z, b2.w);
      q1.z = pack2(b3.x, b3.y); q1.w = pack2(b3.z, b3.w);
      *(uint4*)&Bs[r * 40 + ch] = q0;
      *(uint4*)&Bs[r * 40 + ch + 8] = q1;
    }
    __syncthreads();

    short8 af[4], bfv[4];
    const int kk = (lane >> 4) * 8;
#pragma unroll
    for (int i = 0; i < 4; i++)
      af[i] = *(const short8*)&As[(wm * 64 + i * 16 + (lane & 15)) * 40 + kk];
#pragma unroll
    for (int j = 0; j < 4; j++)
      bfv[j] = *(const short8*)&Bs[(wn * 64 + j * 16 + (lane & 15)) * 40 + kk];
#pragma unroll
    for (int i = 0; i < 4; i++)
#pragma unroll
      for (int j = 0; j < 4; j++)
        acc[i][j] = __builtin_amdgcn_mfma_f32_16x16x32_bf16(af[i], bfv[j], acc[i][j], 0, 0, 0);
    __syncthreads();
  }

#pragma unroll
  for (int j = 0; j < 4; j++) {
    const int g = bx * 128 + wn * 64 + j * 16 + (lane & 15);
    const float bias = b_ih[g] + (g < 1536 ? b_hh[g] : 0.f);
#pragma unroll
    for (int i = 0; i < 4; i++) {
      const int mrow = by * 128 + wm * 64 + i * 16 + (lane >> 4) * 4;
#pragma unroll
      for (int e = 0; e < 4; e++)
        xg[(size_t)(mrow + e) * G3 + g] = f2bf(acc[i][j][e] + bias);
    }
  }
}

// ---------------------------------------------------------------------------
// Persistent sequential GRU scan. 48 blocks, block owns h-units [J0, J0+16).
// W_hh slice (48 rows x 768, bf16) LDS-resident. h state: global bf16,
// double-buffered by step parity; per-step cross-block barrier on cnt[].
// ---------------------------------------------------------------------------
__global__ __launch_bounds__(256) void gru_scan(
    const unsigned short* __restrict__ xg,  // [1024*32][2304] bf16
    const float* __restrict__ Whh,          // [2304][768] fp32
    const float* __restrict__ bhh,          // [2304]
    const float* __restrict__ res_src,      // prev out [32][1024][768] or null
    float* __restrict__ outp,               // out buf or d_out
    unsigned short* __restrict__ hglob,     // [2][32][768] bf16 (parity dbuf)
    unsigned int* __restrict__ cnt,         // [1025]
    int add_res, int final_flip)
{
  extern __shared__ unsigned short Wl[];     // [48][776] bf16
  __shared__ float hgbuf[4][3][32][16];      // [kwave][gate][batch][j]
  __shared__ float bhn_s[16];

  const int tid = threadIdx.x;
  const int lane = tid & 63;
  const int w = tid >> 6;
  const int J0 = blockIdx.x * 16;

  // Load W_hh slice -> LDS (fp32 -> bf16 RNE). Row rr = gate*16 + j.
  for (int idx = tid; idx < 48 * 96; idx += 256) {
    const int rr = idx / 96;
    const int c8 = (idx % 96) * 8;
    const int g = rr >> 4, j = rr & 15;
    const float* p = Whh + (size_t)(g * HDIM + J0 + j) * HDIM + c8;
    float4 v0 = *(const float4*)p;
    float4 v1 = *(const float4*)(p + 4);
    uint4 q;
    q.x = pack2(v0.x, v0.y); q.y = pack2(v0.z, v0.w);
    q.z = pack2(v1.x, v1.y); q.w = pack2(v1.z, v1.w);
    *(uint4*)&Wl[rr * 776 + c8] = q;
  }
  if (tid < 16) bhn_s[tid] = bhh[1536 + J0 + tid];
  __syncthreads();

  // update-phase ownership: pairs p = 2*tid, 2*tid+1  -> batch ub, units uj,uj+1
  const int ub = (tid * 2) >> 4;
  const int uj = (tid * 2) & 15;
  float h_old0 = 0.f, h_old1 = 0.f;

  unsigned pxr, pxz, pxn;
  float2 pres = make_float2(0.f, 0.f);
  {
    const size_t base = (size_t)(0 * 32 + ub) * G3 + J0 + uj;
    pxr = *(const unsigned*)(xg + base);
    pxz = *(const unsigned*)(xg + base + 768);
    pxn = *(const unsigned*)(xg + base + 1536);
    if (add_res)
      pres = *(const float2*)(res_src + ((size_t)ub * T_LEN + (T_LEN - 1)) * HDIM + J0 + uj);
  }

  for (int t = 0; t < T_LEN; ++t) {
    if (t > 0) {
      if (tid == 0) {
        while (__hip_atomic_load(&cnt[t], __ATOMIC_ACQUIRE, __HIP_MEMORY_SCOPE_AGENT) < NBLK)
          __builtin_amdgcn_s_sleep(1);
      }
      __syncthreads();
    }

    const unsigned short* hbase = hglob + (size_t)(t & 1) * (NBATCH * HDIM);

    // MFMA phase: wave w covers K-tiles kt = w*6 .. w*6+5
    f32x4 acc[3][2];
#pragma unroll
    for (int g = 0; g < 3; g++)
#pragma unroll
      for (int mt = 0; mt < 2; mt++) acc[g][mt] = (f32x4){0.f, 0.f, 0.f, 0.f};

#pragma unroll
    for (int kk = 0; kk < 6; ++kk) {
      const int k0 = (w * 6 + kk) * 32 + (lane >> 4) * 8;
      short8 a0 = *(const short8*)(hbase + ((lane & 15) * HDIM + k0));
      short8 a1 = *(const short8*)(hbase + (((lane & 15) + 16) * HDIM + k0));
#pragma unroll
      for (int g = 0; g < 3; ++g) {
        short8 bfr = *(const short8*)&Wl[(g * 16 + (lane & 15)) * 776 + k0];
        acc[g][0] = __builtin_amdgcn_mfma_f32_16x16x32_bf16(a0, bfr, acc[g][0], 0, 0, 0);
        acc[g][1] = __builtin_amdgcn_mfma_f32_16x16x32_bf16(a1, bfr, acc[g][1], 0, 0, 0);
      }
    }

#pragma unroll
    for (int g = 0; g < 3; ++g)
#pragma unroll
      for (int mt = 0; mt < 2; ++mt)
#pragma unroll
        for (int e = 0; e < 4; ++e)
          hgbuf[w][g][mt * 16 + (lane >> 4) * 4 + e][lane & 15] = acc[g][mt][e];
    __syncthreads();

    // Update phase (all 256 threads, 2 units each)
    const float hr0 = hgbuf[0][0][ub][uj] + hgbuf[1][0][ub][uj] + hgbuf[2][0][ub][uj] + hgbuf[3][0][ub][uj];
    const float hz0 = hgbuf[0][1][ub][uj] + hgbuf[1][1][ub][uj] + hgbuf[2][1][ub][uj] + hgbuf[3][1][ub][uj];
    const float hn0 = hgbuf[0][2][ub][uj] + hgbuf[1][2][ub][uj] + hgbuf[2][2][ub][uj] + hgbuf[3][2][ub][uj];
    const float hr1 = hgbuf[0][0][ub][uj+1] + hgbuf[1][0][ub][uj+1] + hgbuf[2][0][ub][uj+1] + hgbuf[3][0][ub][uj+1];
    const float hz1 = hgbuf[0][1][ub][uj+1] + hgbuf[1][1][ub][uj+1] + hgbuf[2][1][ub][uj+1] + hgbuf[3][1][ub][uj+1];
    const float hn1 = hgbuf[0][2][ub][uj+1] + hgbuf[1][2][ub][uj+1] + hgbuf[2][2][ub][uj+1] + hgbuf[3][2][ub][uj+1];

    const float r0 = sigm(bf2f(pxr & 0xffffu) + hr0);
    const float z0 = sigm(bf2f(pxz & 0xffffu) + hz0);
    const float n0 = tanhf(bf2f(pxn & 0xffffu) + r0 * (hn0 + bhn_s[uj]));
    const float r1 = sigm(bf2f(pxr >> 16) + hr1);
    const float z1 = sigm(bf2f(pxz >> 16) + hz1);
    const float n1 = tanhf(bf2f(pxn >> 16) + r1 * (hn1 + bhn_s[uj + 1]));
    const float hnew0 = (1.f - z0) * n0 + z0 * h_old0;
    const float hnew1 = (1.f - z1) * n1 + z1 * h_old1;
    h_old0 = hnew0; h_old1 = hnew1;

    const float o0 = hnew0 + (add_res ? pres.x : 0.f);
    const float o1 = hnew1 + (add_res ? pres.y : 0.f);
    const size_t orow = final_flip ? ((size_t)ub * T_LEN + (T_LEN - 1 - t))
                                   : ((size_t)ub * T_LEN + t);
    *(float2*)(outp + orow * HDIM + J0 + uj) = make_float2(o0, o1);

    unsigned short* hnb = hglob + (size_t)((t + 1) & 1) * (NBATCH * HDIM);
    *(unsigned*)(hnb + ub * HDIM + J0 + uj) = pack2(hnew0, hnew1);

    // Prefetch next step's xg / residual into registers (pre-barrier)
    if (t + 1 < T_LEN) {
      const size_t base = ((size_t)(t + 1) * 32 + ub) * G3 + J0 + uj;
      pxr = *(const unsigned*)(xg + base);
      pxz = *(const unsigned*)(xg + base + 768);
      pxn = *(const unsigned*)(xg + base + 1536);
      if (add_res)
        pres = *(const float2*)(res_src + ((size_t)ub * T_LEN + (T_LEN - 2 - t)) * HDIM + J0 + uj);
    }

    __threadfence();
    __syncthreads();
    if (tid == 0)
      __hip_atomic_fetch_add(&cnt[t + 1], 1u, __ATOMIC_RELEASE, __HIP_MEMORY_SCOPE_AGENT);
  }
}

// ---------------------------------------------------------------------------
extern "C" void kernel_launch(void* const* d_in, const int* in_sizes, int n_in,
                              void* d_out, int out_size, void* d_ws, size_t ws_size,
                              hipStream_t stream) {
  const float* x      = (const float*)d_in[0];
  const float* W_ih0  = (const float*)d_in[1];
  const float* W_hh0  = (const float*)d_in[2];
  const float* b_ih0  = (const float*)d_in[3];
  const float* b_hh0  = (const float*)d_in[4];
  const float* W_ih_s = (const float*)d_in[5];
  const float* W_hh_s = (const float*)d_in[6];
  const float* b_ih_s = (const float*)d_in[7];
  const float* b_hh_s = (const float*)d_in[8];
  float* out = (float*)d_out;

  char* ws = (char*)d_ws;
  size_t off = 0;
  auto alloc = [&](size_t bytes) -> void* {
    void* p = ws + off; off += (bytes + 255) & ~(size_t)255; return p;
  };
  unsigned short* xg = (unsigned short*)alloc((size_t)T_LEN * 32 * G3 * 2);
  float* buf0 = (float*)alloc((size_t)32 * T_LEN * HDIM * 4);
  float* buf1 = (float*)alloc((size_t)32 * T_LEN * HDIM * 4);
  unsigned short* hglob = (unsigned short*)alloc(2 * NBATCH * HDIM * 2);
  unsigned int* cnt = (unsigned int*)alloc((T_LEN + 1) * 4);

  hipFuncSetAttribute((const void*)gru_scan,
                      hipFuncAttributeMaxDynamicSharedMemorySize, 48 * 776 * 2);

  for (int l = 0; l < 4; ++l) {
    const float* src = (l == 0) ? x : ((l == 2) ? buf1 : buf0);
    float* dst = (l == 3) ? out : ((l == 1) ? buf1 : buf0);
    const float* Wih = (l == 0) ? W_ih0 : W_ih_s + (size_t)(l - 1) * G3 * HDIM;
    const float* Whh = (l == 0) ? W_hh0 : W_hh_s + (size_t)(l - 1) * G3 * HDIM;
    const float* bih = (l == 0) ? b_ih0 : b_ih_s + (size_t)(l - 1) * G3;
    const float* bhh = (l == 0) ? b_hh0 : b_hh_s + (size_t)(l - 1) * G3;

    hipMemsetAsync(hglob, 0, 2 * NBATCH * HDIM * 2, stream);
    hipMemsetAsync(cnt, 0, (T_LEN + 1) * 4, stream);

    gemm_xg<<<dim3(18 * 256), dim3(256), 0, stream>>>(src, Wih, bih, bhh, xg, l > 0 ? 1 : 0);

    gru_scan<<<dim3(NBLK), dim3(256), 48 * 776 * 2, stream>>>(
        xg, Whh, bhh, (l > 0) ? src : nullptr, dst, hglob, cnt,
        l > 0 ? 1 : 0, l == 3 ? 1 : 0);
  }
}

// Round 3
// 27093.494 us; speedup vs baseline: 1.6234x; 1.6234x over previous
//
#include <hip/hip_runtime.h>
#include <hip/hip_bf16.h>
#include <stdint.h>

#define T_LEN 1024
#define NBATCH 32
#define HDIM 768
#define G3 2304
#define NBLK 48

typedef __attribute__((ext_vector_type(8))) short short8;
typedef __attribute__((ext_vector_type(4))) float f32x4;
typedef unsigned long long u64;

__device__ __forceinline__ unsigned short f2bf(float f) {
  union { float f; unsigned u; } v; v.f = f;
  return (unsigned short)((v.u + 0x7FFFu + ((v.u >> 16) & 1u)) >> 16);
}
__device__ __forceinline__ float bf2f(unsigned hs) {  // low 16 bits used
  union { unsigned u; float f; } v; v.u = hs << 16; return v.f;
}
__device__ __forceinline__ unsigned pack2(float a, float b) {
  return (unsigned)f2bf(a) | ((unsigned)f2bf(b) << 16);
}
__device__ __forceinline__ float sigm(float x) { return 1.f / (1.f + __expf(-x)); }

// ---------------------------------------------------------------------------
// Input projection GEMM: xg[m][g] = sum_k A[m][k] * W[g][k] + bias(g)
//   A row m = t*32 + b ; A data = src[b][t] (or src[b][1023-t] if flip)
//   bias(g) = b_ih[g] + (g < 1536 ? b_hh[g] : 0)   (b_hhn stays in the scan)
//   output bf16, layout [t][b][2304]  (m-major == t,b-major)
// ---------------------------------------------------------------------------
__global__ __launch_bounds__(256) void gemm_xg(
    const float* __restrict__ src, const float* __restrict__ W,
    const float* __restrict__ b_ih, const float* __restrict__ b_hh,
    unsigned short* __restrict__ xg, int flip)
{
  __shared__ unsigned short As[128 * 40];
  __shared__ unsigned short Bs[128 * 40];

  const int bx = blockIdx.x % 18;   // N tile (2304/128)
  const int by = blockIdx.x / 18;   // M tile (32768/128)
  const int tid = threadIdx.x;
  const int lane = tid & 63;
  const int w = tid >> 6;
  const int wm = w & 1, wn = w >> 1;

  f32x4 acc[4][4];
#pragma unroll
  for (int i = 0; i < 4; i++)
#pragma unroll
    for (int j = 0; j < 4; j++) acc[i][j] = (f32x4){0.f, 0.f, 0.f, 0.f};

  const int r = tid >> 1;
  const int ch = (tid & 1) * 16;

  const int m = by * 128 + r;
  const int tt = m >> 5, bb = m & 31;
  const int srow = flip ? (bb * T_LEN + (T_LEN - 1 - tt)) : (bb * T_LEN + tt);
  const float* arow = src + (size_t)srow * HDIM;
  const int gn = bx * 128 + r;
  const float* brow = W + (size_t)gn * HDIM;

  for (int k0 = 0; k0 < HDIM; k0 += 32) {
    {
      const float4* pa = (const float4*)(arow + k0 + ch);
      float4 a0 = pa[0], a1 = pa[1], a2 = pa[2], a3 = pa[3];
      uint4 q0, q1;
      q0.x = pack2(a0.x, a0.y); q0.y = pack2(a0.z, a0.w);
      q0.z = pack2(a1.x, a1.y); q0.w = pack2(a1.z, a1.w);
      q1.x = pack2(a2.x, a2.y); q1.y = pack2(a2.z, a2.w);
      q1.z = pack2(a3.x, a3.y); q1.w = pack2(a3.z, a3.w);
      *(uint4*)&As[r * 40 + ch] = q0;
      *(uint4*)&As[r * 40 + ch + 8] = q1;

      const float4* pb = (const float4*)(brow + k0 + ch);
      float4 b0 = pb[0], b1 = pb[1], b2 = pb[2], b3 = pb[3];
      q0.x = pack2(b0.x, b0.y); q0.y = pack2(b0.z, b0.w);
      q0.z = pack2(b1.x, b1.y); q0.w = pack2(b1.z, b1.w);
      q1.x = pack2(b2.x, b2.y); q1.y = pack2(b2.z, b2.w);
      q1.z = pack2(b3.x, b3.y); q1.w = pack2(b3.z, b3.w);
      *(uint4*)&Bs[r * 40 + ch] = q0;
      *(uint4*)&Bs[r * 40 + ch + 8] = q1;
    }
    __syncthreads();

    short8 af[4], bfv[4];
    const int kk = (lane >> 4) * 8;
#pragma unroll
    for (int i = 0; i < 4; i++)
      af[i] = *(const short8*)&As[(wm * 64 + i * 16 + (lane & 15)) * 40 + kk];
#pragma unroll
    for (int j = 0; j < 4; j++)
      bfv[j] = *(const short8*)&Bs[(wn * 64 + j * 16 + (lane & 15)) * 40 + kk];
#pragma unroll
    for (int i = 0; i < 4; i++)
#pragma unroll
      for (int j = 0; j < 4; j++)
        acc[i][j] = __builtin_amdgcn_mfma_f32_16x16x32_bf16(af[i], bfv[j], acc[i][j], 0, 0, 0);
    __syncthreads();
  }

#pragma unroll
  for (int j = 0; j < 4; j++) {
    const int g = bx * 128 + wn * 64 + j * 16 + (lane & 15);
    const float bias = b_ih[g] + (g < 1536 ? b_hh[g] : 0.f);
#pragma unroll
    for (int i = 0; i < 4; i++) {
      const int mrow = by * 128 + wm * 64 + i * 16 + (lane >> 4) * 4;
#pragma unroll
      for (int e = 0; e < 4; e++)
        xg[(size_t)(mrow + e) * G3 + g] = f2bf(acc[i][j][e] + bias);
    }
  }
}

// ---------------------------------------------------------------------------
// Persistent sequential GRU scan. 48 blocks, block owns h-units [J0, J0+16).
// W_hh slice (48 rows x 768 bf16) LDS-resident. All cross-block state (h,
// flags) uses RELAXED agent-scope atomics (sc1 -> coherence point directly;
// no buffer_inv / buffer_wbl2 cache maintenance ever). Per-step barrier:
// each block stores its own epoch flag; readers poll 48 flags in parallel.
// ---------------------------------------------------------------------------
__global__ __launch_bounds__(256) void gru_scan(
    const unsigned short* __restrict__ xg,  // [1024*32][2304] bf16
    const float* __restrict__ Whh,          // [2304][768] fp32
    const float* __restrict__ bhh,          // [2304]
    const float* __restrict__ res_src,      // prev out [32][1024][768] or null
    float* __restrict__ outp,               // out buf or d_out
    unsigned* __restrict__ hglob,           // [2][32][384] dwords (2xbf16 each)
    unsigned* __restrict__ flags,           // [64] per-block epoch
    int add_res, int final_flip)
{
  extern __shared__ unsigned short Wl[];     // [48][776] bf16
  __shared__ float hgbuf[4][3][32][16];      // [kwave][gate][batch][j]
  __shared__ float bhn_s[16];

  const int tid = threadIdx.x;
  const int lane = tid & 63;
  const int w = tid >> 6;
  const int J0 = blockIdx.x * 16;

  // Load W_hh slice -> LDS (fp32 -> bf16 RNE). Row rr = gate*16 + j.
  for (int idx = tid; idx < 48 * 96; idx += 256) {
    const int rr = idx / 96;
    const int c8 = (idx % 96) * 8;
    const int g = rr >> 4, j = rr & 15;
    const float* p = Whh + (size_t)(g * HDIM + J0 + j) * HDIM + c8;
    float4 v0 = *(const float4*)p;
    float4 v1 = *(const float4*)(p + 4);
    uint4 q;
    q.x = pack2(v0.x, v0.y); q.y = pack2(v0.z, v0.w);
    q.z = pack2(v1.x, v1.y); q.w = pack2(v1.z, v1.w);
    *(uint4*)&Wl[rr * 776 + c8] = q;
  }
  if (tid < 16) bhn_s[tid] = bhh[1536 + J0 + tid];
  __syncthreads();

  // update-phase ownership: pairs p = 2*tid, 2*tid+1  -> batch ub, units uj,uj+1
  const int ub = (tid * 2) >> 4;
  const int uj = (tid * 2) & 15;
  float h_old0 = 0.f, h_old1 = 0.f;

  unsigned pxr, pxz, pxn;
  float2 pres = make_float2(0.f, 0.f);
  {
    const size_t base = (size_t)(0 * 32 + ub) * G3 + J0 + uj;
    pxr = *(const unsigned*)(xg + base);
    pxz = *(const unsigned*)(xg + base + 768);
    pxn = *(const unsigned*)(xg + base + 1536);
    if (add_res)
      pres = *(const float2*)(res_src + ((size_t)ub * T_LEN + (T_LEN - 1)) * HDIM + J0 + uj);
  }

  const u64* __restrict__ hq = (const u64*)hglob;  // [2][32*192] qwords

  for (int t = 0; t < T_LEN; ++t) {
    if (t > 0) {
      const unsigned want = (unsigned)t;
      for (;;) {
        unsigned f = 0xFFFFFFFFu;
        if (lane < NBLK)
          f = __hip_atomic_load(&flags[lane], __ATOMIC_RELAXED, __HIP_MEMORY_SCOPE_AGENT);
        if (__all((int)(f >= want))) break;
      }
      asm volatile("" ::: "memory");  // keep h loads below the spin
    }

    // h_t base: 32 rows x 192 qwords (768 bf16) per buffer
    const u64* hb = hq + (size_t)(t & 1) * (NBATCH * HDIM / 4);

    // MFMA phase: wave w covers K-tiles kt = w*6 .. w*6+5.
    // A-fragments read straight from the coherence point (relaxed agent 8B).
    f32x4 acc[3][2];
#pragma unroll
    for (int g = 0; g < 3; g++)
#pragma unroll
      for (int mt = 0; mt < 2; mt++) acc[g][mt] = (f32x4){0.f, 0.f, 0.f, 0.f};

#pragma unroll
    for (int kk = 0; kk < 6; ++kk) {
      const int kt = w * 6 + kk;
      const int k0 = kt * 32 + (lane >> 4) * 8;     // element offset in row
      const int qi0 = (lane & 15) * 192 + (k0 >> 2);        // qword index
      const int qi1 = qi0 + 16 * 192;
      union { u64 q[2]; short8 s; } ua0, ua1;
      ua0.q[0] = __hip_atomic_load(&hb[qi0],     __ATOMIC_RELAXED, __HIP_MEMORY_SCOPE_AGENT);
      ua0.q[1] = __hip_atomic_load(&hb[qi0 + 1], __ATOMIC_RELAXED, __HIP_MEMORY_SCOPE_AGENT);
      ua1.q[0] = __hip_atomic_load(&hb[qi1],     __ATOMIC_RELAXED, __HIP_MEMORY_SCOPE_AGENT);
      ua1.q[1] = __hip_atomic_load(&hb[qi1 + 1], __ATOMIC_RELAXED, __HIP_MEMORY_SCOPE_AGENT);
#pragma unroll
      for (int g = 0; g < 3; ++g) {
        short8 bfr = *(const short8*)&Wl[(g * 16 + (lane & 15)) * 776 + k0];
        acc[g][0] = __builtin_amdgcn_mfma_f32_16x16x32_bf16(ua0.s, bfr, acc[g][0], 0, 0, 0);
        acc[g][1] = __builtin_amdgcn_mfma_f32_16x16x32_bf16(ua1.s, bfr, acc[g][1], 0, 0, 0);
      }
    }

#pragma unroll
    for (int g = 0; g < 3; ++g)
#pragma unroll
      for (int mt = 0; mt < 2; ++mt)
#pragma unroll
        for (int e = 0; e < 4; ++e)
          hgbuf[w][g][mt * 16 + (lane >> 4) * 4 + e][lane & 15] = acc[g][mt][e];
    __syncthreads();

    // Update phase (all 256 threads, 2 units each)
    const float hr0 = hgbuf[0][0][ub][uj] + hgbuf[1][0][ub][uj] + hgbuf[2][0][ub][uj] + hgbuf[3][0][ub][uj];
    const float hz0 = hgbuf[0][1][ub][uj] + hgbuf[1][1][ub][uj] + hgbuf[2][1][ub][uj] + hgbuf[3][1][ub][uj];
    const float hn0 = hgbuf[0][2][ub][uj] + hgbuf[1][2][ub][uj] + hgbuf[2][2][ub][uj] + hgbuf[3][2][ub][uj];
    const float hr1 = hgbuf[0][0][ub][uj+1] + hgbuf[1][0][ub][uj+1] + hgbuf[2][0][ub][uj+1] + hgbuf[3][0][ub][uj+1];
    const float hz1 = hgbuf[0][1][ub][uj+1] + hgbuf[1][1][ub][uj+1] + hgbuf[2][1][ub][uj+1] + hgbuf[3][1][ub][uj+1];
    const float hn1 = hgbuf[0][2][ub][uj+1] + hgbuf[1][2][ub][uj+1] + hgbuf[2][2][ub][uj+1] + hgbuf[3][2][ub][uj+1];

    const float r0 = sigm(bf2f(pxr & 0xffffu) + hr0);
    const float z0 = sigm(bf2f(pxz & 0xffffu) + hz0);
    const float n0 = tanhf(bf2f(pxn & 0xffffu) + r0 * (hn0 + bhn_s[uj]));
    const float r1 = sigm(bf2f(pxr >> 16) + hr1);
    const float z1 = sigm(bf2f(pxz >> 16) + hz1);
    const float n1 = tanhf(bf2f(pxn >> 16) + r1 * (hn1 + bhn_s[uj + 1]));
    const float hnew0 = (1.f - z0) * n0 + z0 * h_old0;
    const float hnew1 = (1.f - z1) * n1 + z1 * h_old1;
    h_old0 = hnew0; h_old1 = hnew1;

    const float o0 = hnew0 + (add_res ? pres.x : 0.f);
    const float o1 = hnew1 + (add_res ? pres.y : 0.f);
    const size_t orow = final_flip ? ((size_t)ub * T_LEN + (T_LEN - 1 - t))
                                   : ((size_t)ub * T_LEN + t);
    *(float2*)(outp + orow * HDIM + J0 + uj) = make_float2(o0, o1);

    // h_{t+1} store: relaxed agent (sc1 write-through to coherence point)
    unsigned* hnb = hglob + (size_t)((t + 1) & 1) * (NBATCH * HDIM / 2);
    __hip_atomic_store(&hnb[ub * 384 + ((J0 + uj) >> 1)], pack2(hnew0, hnew1),
                       __ATOMIC_RELAXED, __HIP_MEMORY_SCOPE_AGENT);

    // Prefetch next step's xg / residual (latency hides under drain + spin)
    if (t + 1 < T_LEN) {
      const size_t base = ((size_t)(t + 1) * 32 + ub) * G3 + J0 + uj;
      pxr = *(const unsigned*)(xg + base);
      pxz = *(const unsigned*)(xg + base + 768);
      pxn = *(const unsigned*)(xg + base + 1536);
      if (add_res)
        pres = *(const float2*)(res_src + ((size_t)ub * T_LEN + (T_LEN - 2 - t)) * HDIM + J0 + uj);
    }

    // Drain this wave's stores, then block-wide rendezvous, then publish epoch.
    asm volatile("s_waitcnt vmcnt(0)" ::: "memory");
    __syncthreads();
    if (tid == 0)
      __hip_atomic_store(&flags[blockIdx.x], (unsigned)(t + 1),
                         __ATOMIC_RELAXED, __HIP_MEMORY_SCOPE_AGENT);
  }
}

// ---------------------------------------------------------------------------
extern "C" void kernel_launch(void* const* d_in, const int* in_sizes, int n_in,
                              void* d_out, int out_size, void* d_ws, size_t ws_size,
                              hipStream_t stream) {
  const float* x      = (const float*)d_in[0];
  const float* W_ih0  = (const float*)d_in[1];
  const float* W_hh0  = (const float*)d_in[2];
  const float* b_ih0  = (const float*)d_in[3];
  const float* b_hh0  = (const float*)d_in[4];
  const float* W_ih_s = (const float*)d_in[5];
  const float* W_hh_s = (const float*)d_in[6];
  const float* b_ih_s = (const float*)d_in[7];
  const float* b_hh_s = (const float*)d_in[8];
  float* out = (float*)d_out;

  char* ws = (char*)d_ws;
  size_t off = 0;
  auto alloc = [&](size_t bytes) -> void* {
    void* p = ws + off; off += (bytes + 255) & ~(size_t)255; return p;
  };
  unsigned short* xg = (unsigned short*)alloc((size_t)T_LEN * 32 * G3 * 2);
  float* buf0 = (float*)alloc((size_t)32 * T_LEN * HDIM * 4);
  float* buf1 = (float*)alloc((size_t)32 * T_LEN * HDIM * 4);
  unsigned* hglob = (unsigned*)alloc(2 * NBATCH * HDIM * 2);
  unsigned* flags = (unsigned*)alloc(64 * 4);

  hipFuncSetAttribute((const void*)gru_scan,
                      hipFuncAttributeMaxDynamicSharedMemorySize, 48 * 776 * 2);

  for (int l = 0; l < 4; ++l) {
    const float* src = (l == 0) ? x : ((l == 2) ? buf1 : buf0);
    float* dst = (l == 3) ? out : ((l == 1) ? buf1 : buf0);
    const float* Wih = (l == 0) ? W_ih0 : W_ih_s + (size_t)(l - 1) * G3 * HDIM;
    const float* Whh = (l == 0) ? W_hh0 : W_hh_s + (size_t)(l - 1) * G3 * HDIM;
    const float* bih = (l == 0) ? b_ih0 : b_ih_s + (size_t)(l - 1) * G3;
    const float* bhh = (l == 0) ? b_hh0 : b_hh_s + (size_t)(l - 1) * G3;

    hipMemsetAsync(hglob, 0, 2 * NBATCH * HDIM * 2, stream);
    hipMemsetAsync(flags, 0, 64 * 4, stream);

    gemm_xg<<<dim3(18 * 256), dim3(256), 0, stream>>>(src, Wih, bih, bhh, xg, l > 0 ? 1 : 0);

    gru_scan<<<dim3(NBLK), dim3(256), 48 * 776 * 2, stream>>>(
        xg, Whh, bhh, (l > 0) ? src : nullptr, dst, hglob, flags,
        l > 0 ? 1 : 0, l == 3 ? 1 : 0);
  }
}

// Round 4
// 23585.204 us; speedup vs baseline: 1.8649x; 1.1487x over previous
//
#include <hip/hip_runtime.h>
#include <hip/hip_bf16.h>
#include <stdint.h>

#define T_LEN 1024
#define NBATCH 32
#define HDIM 768
#define G3 2304
#define NBLK 48

typedef __attribute__((ext_vector_type(8))) short short8;
typedef __attribute__((ext_vector_type(4))) float f32x4;
typedef unsigned long long u64;

__device__ __forceinline__ unsigned short f2bf(float f) {
  union { float f; unsigned u; } v; v.f = f;
  return (unsigned short)((v.u + 0x7FFFu + ((v.u >> 16) & 1u)) >> 16);
}
__device__ __forceinline__ float bf2f(unsigned hs) {  // low 16 bits used
  union { unsigned u; float f; } v; v.u = hs << 16; return v.f;
}
__device__ __forceinline__ unsigned pack2(float a, float b) {
  return (unsigned)f2bf(a) | ((unsigned)f2bf(b) << 16);
}
// fast sigmoid/tanh: v_exp + rcp, no libm branches. inf-safe.
__device__ __forceinline__ float sigm(float x) {
  return __fdividef(1.f, 1.f + __expf(-x));
}
__device__ __forceinline__ float ftanh(float x) {
  return 1.f - __fdividef(2.f, __expf(2.f * x) + 1.f);
}

// ---------------------------------------------------------------------------
// Input projection GEMM: xg[m][g] = sum_k A[m][k] * W[g][k] + bias(g)
//   A row m = t*32 + b ; A data = src[b][t] (or src[b][1023-t] if flip)
//   bias(g) = b_ih[g] + (g < 1536 ? b_hh[g] : 0)   (b_hhn stays in the scan)
//   output bf16, layout [t][b][2304]  (m-major == t,b-major)
// ---------------------------------------------------------------------------
__global__ __launch_bounds__(256) void gemm_xg(
    const float* __restrict__ src, const float* __restrict__ W,
    const float* __restrict__ b_ih, const float* __restrict__ b_hh,
    unsigned short* __restrict__ xg, int flip)
{
  __shared__ unsigned short As[128 * 40];
  __shared__ unsigned short Bs[128 * 40];

  const int bx = blockIdx.x % 18;   // N tile (2304/128)
  const int by = blockIdx.x / 18;   // M tile (32768/128)
  const int tid = threadIdx.x;
  const int lane = tid & 63;
  const int w = tid >> 6;
  const int wm = w & 1, wn = w >> 1;

  f32x4 acc[4][4];
#pragma unroll
  for (int i = 0; i < 4; i++)
#pragma unroll
    for (int j = 0; j < 4; j++) acc[i][j] = (f32x4){0.f, 0.f, 0.f, 0.f};

  const int r = tid >> 1;
  const int ch = (tid & 1) * 16;

  const int m = by * 128 + r;
  const int tt = m >> 5, bb = m & 31;
  const int srow = flip ? (bb * T_LEN + (T_LEN - 1 - tt)) : (bb * T_LEN + tt);
  const float* arow = src + (size_t)srow * HDIM;
  const int gn = bx * 128 + r;
  const float* brow = W + (size_t)gn * HDIM;

  for (int k0 = 0; k0 < HDIM; k0 += 32) {
    {
      const float4* pa = (const float4*)(arow + k0 + ch);
      float4 a0 = pa[0], a1 = pa[1], a2 = pa[2], a3 = pa[3];
      uint4 q0, q1;
      q0.x = pack2(a0.x, a0.y); q0.y = pack2(a0.z, a0.w);
      q0.z = pack2(a1.x, a1.y); q0.w = pack2(a1.z, a1.w);
      q1.x = pack2(a2.x, a2.y); q1.y = pack2(a2.z, a2.w);
      q1.z = pack2(a3.x, a3.y); q1.w = pack2(a3.z, a3.w);
      *(uint4*)&As[r * 40 + ch] = q0;
      *(uint4*)&As[r * 40 + ch + 8] = q1;

      const float4* pb = (const float4*)(brow + k0 + ch);
      float4 b0 = pb[0], b1 = pb[1], b2 = pb[2], b3 = pb[3];
      q0.x = pack2(b0.x, b0.y); q0.y = pack2(b0.z, b0.w);
      q0.z = pack2(b1.x, b1.y); q0.w = pack2(b1.z, b1.w);
      q1.x = pack2(b2.x, b2.y); q1.y = pack2(b2.z, b2.w);
      q1.z = pack2(b3.x, b3.y); q1.w = pack2(b3.z, b3.w);
      *(uint4*)&Bs[r * 40 + ch] = q0;
      *(uint4*)&Bs[r * 40 + ch + 8] = q1;
    }
    __syncthreads();

    short8 af[4], bfv[4];
    const int kk = (lane >> 4) * 8;
#pragma unroll
    for (int i = 0; i < 4; i++)
      af[i] = *(const short8*)&As[(wm * 64 + i * 16 + (lane & 15)) * 40 + kk];
#pragma unroll
    for (int j = 0; j < 4; j++)
      bfv[j] = *(const short8*)&Bs[(wn * 64 + j * 16 + (lane & 15)) * 40 + kk];
#pragma unroll
    for (int i = 0; i < 4; i++)
#pragma unroll
      for (int j = 0; j < 4; j++)
        acc[i][j] = __builtin_amdgcn_mfma_f32_16x16x32_bf16(af[i], bfv[j], acc[i][j], 0, 0, 0);
    __syncthreads();
  }

#pragma unroll
  for (int j = 0; j < 4; j++) {
    const int g = bx * 128 + wn * 64 + j * 16 + (lane & 15);
    const float bias = b_ih[g] + (g < 1536 ? b_hh[g] : 0.f);
#pragma unroll
    for (int i = 0; i < 4; i++) {
      const int mrow = by * 128 + wm * 64 + i * 16 + (lane >> 4) * 4;
#pragma unroll
      for (int e = 0; e < 4; e++)
        xg[(size_t)(mrow + e) * G3 + g] = f2bf(acc[i][j][e] + bias);
    }
  }
}

// ---------------------------------------------------------------------------
// Persistent sequential GRU scan. 48 blocks, block owns h-units [J0, J0+16).
// W_hh slice (48 rows x 768 bf16) LDS-resident. Cross-block state (h, flags)
// via RELAXED agent-scope atomics (sc1 -> LLC directly, no cache maintenance).
// Per step: spin on 48 per-block epoch flags -> issue ALL 24 coherent h-loads
// (one LLC round trip; launch_bounds(256,1) gives the VGPR budget) -> 36 MFMA
// -> cross-wave reduce in LDS -> gate update -> h-store -> vmcnt(0) (drains
// ONLY the h-store) -> barrier -> flag publish -> out-store + prefetch
// (overlap the next spin).
// ---------------------------------------------------------------------------
__global__ __launch_bounds__(256, 1) void gru_scan(
    const unsigned short* __restrict__ xg,  // [1024*32][2304] bf16
    const float* __restrict__ Whh,          // [2304][768] fp32
    const float* __restrict__ bhh,          // [2304]
    const float* __restrict__ res_src,      // prev out [32][1024][768] or null
    float* __restrict__ outp,               // out buf or d_out
    unsigned* __restrict__ hglob,           // [2][32][384] dwords (2xbf16 each)
    unsigned* __restrict__ flags,           // [64] per-block epoch
    int add_res, int final_flip)
{
  extern __shared__ unsigned short Wl[];     // [48][776] bf16
  __shared__ float hgbuf[4][3][32][17];      // [kwave][gate][batch][j] (+1 pad)
  __shared__ float bhn_s[16];

  const int tid = threadIdx.x;
  const int lane = tid & 63;
  const int w = tid >> 6;
  const int J0 = blockIdx.x * 16;

  // Load W_hh slice -> LDS (fp32 -> bf16 RNE). Row rr = gate*16 + j.
  for (int idx = tid; idx < 48 * 96; idx += 256) {
    const int rr = idx / 96;
    const int c8 = (idx % 96) * 8;
    const int g = rr >> 4, j = rr & 15;
    const float* p = Whh + (size_t)(g * HDIM + J0 + j) * HDIM + c8;
    float4 v0 = *(const float4*)p;
    float4 v1 = *(const float4*)(p + 4);
    uint4 q;
    q.x = pack2(v0.x, v0.y); q.y = pack2(v0.z, v0.w);
    q.z = pack2(v1.x, v1.y); q.w = pack2(v1.z, v1.w);
    *(uint4*)&Wl[rr * 776 + c8] = q;
  }
  if (tid < 16) bhn_s[tid] = bhh[1536 + J0 + tid];
  __syncthreads();

  // update-phase ownership: pairs p = 2*tid, 2*tid+1  -> batch ub, units uj,uj+1
  const int ub = (tid * 2) >> 4;
  const int uj = (tid * 2) & 15;
  float h_old0 = 0.f, h_old1 = 0.f;

  unsigned pxr, pxz, pxn;
  float2 pres = make_float2(0.f, 0.f);
  {
    const size_t base = (size_t)(0 * 32 + ub) * G3 + J0 + uj;
    pxr = *(const unsigned*)(xg + base);
    pxz = *(const unsigned*)(xg + base + 768);
    pxn = *(const unsigned*)(xg + base + 1536);
    if (add_res)
      pres = *(const float2*)(res_src + ((size_t)ub * T_LEN + (T_LEN - 1)) * HDIM + J0 + uj);
  }

  const u64* __restrict__ hq = (const u64*)hglob;  // [2][32*192] qwords

  for (int t = 0; t < T_LEN; ++t) {
    if (t > 0) {
      const unsigned want = (unsigned)t;
      for (;;) {
        unsigned f = 0xFFFFFFFFu;
        if (lane < NBLK)
          f = __hip_atomic_load(&flags[lane], __ATOMIC_RELAXED, __HIP_MEMORY_SCOPE_AGENT);
        if (__all((int)(f >= want))) break;
      }
      asm volatile("" ::: "memory");  // keep h loads below the spin
    }

    // h_t base: 32 rows x 192 qwords (768 bf16) per buffer
    const u64* hb = hq + (size_t)(t & 1) * (NBATCH * HDIM / 4);

    // ---- Issue ALL 24 coherent h-loads first (one LLC round trip) ----
    u64 h0q[6][2], h1q[6][2];
#pragma unroll
    for (int kk = 0; kk < 6; ++kk) {
      const int k0 = (w * 6 + kk) * 32 + (lane >> 4) * 8;   // elem offset in row
      const int qi0 = (lane & 15) * 192 + (k0 >> 2);        // qword index
      const int qi1 = qi0 + 16 * 192;
      h0q[kk][0] = __hip_atomic_load(&hb[qi0],     __ATOMIC_RELAXED, __HIP_MEMORY_SCOPE_AGENT);
      h0q[kk][1] = __hip_atomic_load(&hb[qi0 + 1], __ATOMIC_RELAXED, __HIP_MEMORY_SCOPE_AGENT);
      h1q[kk][0] = __hip_atomic_load(&hb[qi1],     __ATOMIC_RELAXED, __HIP_MEMORY_SCOPE_AGENT);
      h1q[kk][1] = __hip_atomic_load(&hb[qi1 + 1], __ATOMIC_RELAXED, __HIP_MEMORY_SCOPE_AGENT);
    }

    // ---- MFMA phase: wave w covers K-tiles kt = w*6 .. w*6+5 ----
    f32x4 acc[3][2];
#pragma unroll
    for (int g = 0; g < 3; g++)
#pragma unroll
      for (int mt = 0; mt < 2; mt++) acc[g][mt] = (f32x4){0.f, 0.f, 0.f, 0.f};

#pragma unroll
    for (int kk = 0; kk < 6; ++kk) {
      const int k0 = (w * 6 + kk) * 32 + (lane >> 4) * 8;
      union { u64 q[2]; short8 s; } ua0, ua1;
      ua0.q[0] = h0q[kk][0]; ua0.q[1] = h0q[kk][1];
      ua1.q[0] = h1q[kk][0]; ua1.q[1] = h1q[kk][1];
#pragma unroll
      for (int g = 0; g < 3; ++g) {
        short8 bfr = *(const short8*)&Wl[(g * 16 + (lane & 15)) * 776 + k0];
        acc[g][0] = __builtin_amdgcn_mfma_f32_16x16x32_bf16(ua0.s, bfr, acc[g][0], 0, 0, 0);
        acc[g][1] = __builtin_amdgcn_mfma_f32_16x16x32_bf16(ua1.s, bfr, acc[g][1], 0, 0, 0);
      }
    }

#pragma unroll
    for (int g = 0; g < 3; ++g)
#pragma unroll
      for (int mt = 0; mt < 2; ++mt)
#pragma unroll
        for (int e = 0; e < 4; ++e)
          hgbuf[w][g][mt * 16 + (lane >> 4) * 4 + e][lane & 15] = acc[g][mt][e];
    __syncthreads();

    // ---- Update phase (all 256 threads, 2 units each) ----
    const float hr0 = hgbuf[0][0][ub][uj] + hgbuf[1][0][ub][uj] + hgbuf[2][0][ub][uj] + hgbuf[3][0][ub][uj];
    const float hz0 = hgbuf[0][1][ub][uj] + hgbuf[1][1][ub][uj] + hgbuf[2][1][ub][uj] + hgbuf[3][1][ub][uj];
    const float hn0 = hgbuf[0][2][ub][uj] + hgbuf[1][2][ub][uj] + hgbuf[2][2][ub][uj] + hgbuf[3][2][ub][uj];
    const float hr1 = hgbuf[0][0][ub][uj+1] + hgbuf[1][0][ub][uj+1] + hgbuf[2][0][ub][uj+1] + hgbuf[3][0][ub][uj+1];
    const float hz1 = hgbuf[0][1][ub][uj+1] + hgbuf[1][1][ub][uj+1] + hgbuf[2][1][ub][uj+1] + hgbuf[3][1][ub][uj+1];
    const float hn1 = hgbuf[0][2][ub][uj+1] + hgbuf[1][2][ub][uj+1] + hgbuf[2][2][ub][uj+1] + hgbuf[3][2][ub][uj+1];

    const float r0 = sigm(bf2f(pxr & 0xffffu) + hr0);
    const float z0 = sigm(bf2f(pxz & 0xffffu) + hz0);
    const float n0 = ftanh(bf2f(pxn & 0xffffu) + r0 * (hn0 + bhn_s[uj]));
    const float r1 = sigm(bf2f(pxr >> 16) + hr1);
    const float z1 = sigm(bf2f(pxz >> 16) + hz1);
    const float n1 = ftanh(bf2f(pxn >> 16) + r1 * (hn1 + bhn_s[uj + 1]));
    const float hnew0 = (1.f - z0) * n0 + z0 * h_old0;
    const float hnew1 = (1.f - z1) * n1 + z1 * h_old1;
    h_old0 = hnew0; h_old1 = hnew1;

    // ---- h_{t+1} store, drain ONLY it, rendezvous, publish epoch ----
    unsigned* hnb = hglob + (size_t)((t + 1) & 1) * (NBATCH * HDIM / 2);
    __hip_atomic_store(&hnb[ub * 384 + ((J0 + uj) >> 1)], pack2(hnew0, hnew1),
                       __ATOMIC_RELAXED, __HIP_MEMORY_SCOPE_AGENT);
    asm volatile("s_waitcnt vmcnt(0)" ::: "memory");
    __syncthreads();
    if (tid == 0)
      __hip_atomic_store(&flags[blockIdx.x], (unsigned)(t + 1),
                         __ATOMIC_RELAXED, __HIP_MEMORY_SCOPE_AGENT);

    // ---- Off critical path: out-store + next-step prefetch (overlap spin) ----
    const float o0 = hnew0 + (add_res ? pres.x : 0.f);
    const float o1 = hnew1 + (add_res ? pres.y : 0.f);
    const size_t orow = final_flip ? ((size_t)ub * T_LEN + (T_LEN - 1 - t))
                                   : ((size_t)ub * T_LEN + t);
    *(float2*)(outp + orow * HDIM + J0 + uj) = make_float2(o0, o1);

    if (t + 1 < T_LEN) {
      const size_t base = ((size_t)(t + 1) * 32 + ub) * G3 + J0 + uj;
      pxr = *(const unsigned*)(xg + base);
      pxz = *(const unsigned*)(xg + base + 768);
      pxn = *(const unsigned*)(xg + base + 1536);
      if (add_res)
        pres = *(const float2*)(res_src + ((size_t)ub * T_LEN + (T_LEN - 2 - t)) * HDIM + J0 + uj);
    }
  }
}

// ---------------------------------------------------------------------------
extern "C" void kernel_launch(void* const* d_in, const int* in_sizes, int n_in,
                              void* d_out, int out_size, void* d_ws, size_t ws_size,
                              hipStream_t stream) {
  const float* x      = (const float*)d_in[0];
  const float* W_ih0  = (const float*)d_in[1];
  const float* W_hh0  = (const float*)d_in[2];
  const float* b_ih0  = (const float*)d_in[3];
  const float* b_hh0  = (const float*)d_in[4];
  const float* W_ih_s = (const float*)d_in[5];
  const float* W_hh_s = (const float*)d_in[6];
  const float* b_ih_s = (const float*)d_in[7];
  const float* b_hh_s = (const float*)d_in[8];
  float* out = (float*)d_out;

  char* ws = (char*)d_ws;
  size_t off = 0;
  auto alloc = [&](size_t bytes) -> void* {
    void* p = ws + off; off += (bytes + 255) & ~(size_t)255; return p;
  };
  unsigned short* xg = (unsigned short*)alloc((size_t)T_LEN * 32 * G3 * 2);
  float* buf0 = (float*)alloc((size_t)32 * T_LEN * HDIM * 4);
  float* buf1 = (float*)alloc((size_t)32 * T_LEN * HDIM * 4);
  unsigned* hglob = (unsigned*)alloc(2 * NBATCH * HDIM * 2);
  unsigned* flags = (unsigned*)alloc(64 * 4);

  hipFuncSetAttribute((const void*)gru_scan,
                      hipFuncAttributeMaxDynamicSharedMemorySize, 48 * 776 * 2);

  for (int l = 0; l < 4; ++l) {
    const float* src = (l == 0) ? x : ((l == 2) ? buf1 : buf0);
    float* dst = (l == 3) ? out : ((l == 1) ? buf1 : buf0);
    const float* Wih = (l == 0) ? W_ih0 : W_ih_s + (size_t)(l - 1) * G3 * HDIM;
    const float* Whh = (l == 0) ? W_hh0 : W_hh_s + (size_t)(l - 1) * G3 * HDIM;
    const float* bih = (l == 0) ? b_ih0 : b_ih_s + (size_t)(l - 1) * G3;
    const float* bhh = (l == 0) ? b_hh0 : b_hh_s + (size_t)(l - 1) * G3;

    hipMemsetAsync(hglob, 0, 2 * NBATCH * HDIM * 2, stream);
    hipMemsetAsync(flags, 0, 64 * 4, stream);

    gemm_xg<<<dim3(18 * 256), dim3(256), 0, stream>>>(src, Wih, bih, bhh, xg, l > 0 ? 1 : 0);

    gru_scan<<<dim3(NBLK), dim3(256), 48 * 776 * 2, stream>>>(
        xg, Whh, bhh, (l > 0) ? src : nullptr, dst, hglob, flags,
        l > 0 ? 1 : 0, l == 3 ? 1 : 0);
  }
}